// Round 6
// baseline (733.015 us; speedup 1.0000x reference)
//
#include <hip/hip_runtime.h>
#include <stdint.h>

#define N_NODES 100000
#define NPAD    100032
#define DIM 128
#define NNZ_E 1600000
#define SCAN_TILE 2048
#define N_TILES ((N_NODES + SCAN_TILE - 1) / SCAN_TILE)   // 49

// x / side layout is SLICE-MAJOR: 8 slices of 16 cols.
//   ushort idx = (s*NPAD + n)*16 + o,  o in [0,16)
//   unsigned (2 cols): (s*NPAD+n)*8 + l, l in [0,8)
//   uint2 (4 cols):    (s*NPAD+n)*4 + m
//   uint4 (8 cols):    (s*NPAD+n)*2 + h
// Slice s is processed only by blocks with blockIdx%8==s -> lands on XCD s
// (round-robin dispatch), so the 3.2 MB slice stays resident in that XCD's
// 4 MiB L2 and the random gather becomes an L2 hit.

typedef float f32x4  __attribute__((ext_vector_type(4)));
typedef short bf16x8 __attribute__((ext_vector_type(8)));

union B8 { uint4 q; unsigned u[4]; bf16x8 v; };

__device__ __forceinline__ unsigned short f2bs(float f) {   // fp32 -> bf16 RNE
    unsigned u = __builtin_bit_cast(unsigned, f);
    u = (u + 0x7fffu + ((u >> 16) & 1u)) >> 16;
    return (unsigned short)u;
}
// HW packed fp32->bf16 RNE convert: 1 instruction replaces ~8
__device__ __forceinline__ unsigned cvtpk(float lo, float hi) {
    unsigned r;
    asm("v_cvt_pk_bf16_f32 %0, %1, %2" : "=v"(r) : "v"(lo), "v"(hi));
    return r;
}
#define UNPK(u32, flo, fhi) { flo = __builtin_bit_cast(float, (unsigned)((u32) << 16)); \
                              fhi = __builtin_bit_cast(float, (unsigned)((u32) & 0xffff0000u)); }

// ---------------------------------------------------------------------------
// emb -> out[:,0:128] fp32  AND  x (slice-major bf16; pad rows zeroed)
// ---------------------------------------------------------------------------
__global__ __launch_bounds__(256) void copy_emb_kernel(
    const float* __restrict__ emb, float* __restrict__ out,
    unsigned* __restrict__ xbuf)
{
    int tid = blockIdx.x * 256 + threadIdx.x;   // NPAD*32 threads, one float4 each
    int n = tid >> 5, c = tid & 31;             // c = 4-col group (cols 4c..4c+3)
    int s = c >> 2, m = c & 3;                  // slice, uint2 within slice
    uint2* dst = (uint2*)xbuf + ((size_t)s * NPAD + n) * 4 + m;
    if (n < N_NODES) {
        float4 v = ((const float4*)emb)[tid];
        *((float4*)(out + (size_t)n * 384) + c) = v;
        *dst = make_uint2(cvtpk(v.x, v.y), cvtpk(v.z, v.w));
    } else {
        *dst = make_uint2(0u, 0u);
    }
}

// ---------------------------------------------------------------------------
// Fused prep: W fp32 -> bf16 (both layers, both matrices) + zero cnt.
// ---------------------------------------------------------------------------
__global__ __launch_bounds__(256) void prep_kernel(
    const float* __restrict__ W1, const float* __restrict__ W2,
    unsigned* __restrict__ w1b, unsigned* __restrict__ w2b,
    int* __restrict__ cnt)
{
    int tid = blockIdx.x * 256 + threadIdx.x;
    if (tid < 8192) {
        float4 a = ((const float4*)W1)[tid];
        float4 b = ((const float4*)W2)[tid];
        ((uint2*)w1b)[tid] = make_uint2(cvtpk(a.x, a.y), cvtpk(a.z, a.w));
        ((uint2*)w2b)[tid] = make_uint2(cvtpk(b.x, b.y), cvtpk(b.z, b.w));
    }
    if (tid < 25000) ((uint4*)cnt)[tid] = make_uint4(0u, 0u, 0u, 0u);  // 100000 ints
}

// ---------------------------------------------------------------------------
// CSR build: histogram -> scan -> countdown scatter
// ---------------------------------------------------------------------------
__global__ __launch_bounds__(256) void hist_kernel(
    const int* __restrict__ rows, int* __restrict__ cnt)
{
    int e = blockIdx.x * 256 + threadIdx.x;
    atomicAdd(&cnt[rows[e]], 1);
}

__global__ __launch_bounds__(256) void scan_pass_a(
    const int* __restrict__ cnt, int* __restrict__ tile_sums)
{
    __shared__ int sdata[256];
    int base = blockIdx.x * SCAN_TILE + threadIdx.x * 8;
    int s = 0;
    #pragma unroll
    for (int q = 0; q < 8; ++q) {
        int i = base + q;
        s += (i < N_NODES) ? cnt[i] : 0;
    }
    sdata[threadIdx.x] = s;
    __syncthreads();
    for (int off = 128; off >= 1; off >>= 1) {
        if (threadIdx.x < off) sdata[threadIdx.x] += sdata[threadIdx.x + off];
        __syncthreads();
    }
    if (threadIdx.x == 0) tile_sums[blockIdx.x] = sdata[0];
}

// wave-parallel exclusive scan over 49 tile sums
__global__ void scan_pass_b(int* __restrict__ tile_sums)
{
    int lane = threadIdx.x;          // 64 lanes
    int v = (lane < N_TILES) ? tile_sums[lane] : 0;
    #pragma unroll
    for (int off = 1; off < 64; off <<= 1) {
        int u = __shfl_up(v, off);
        if (lane >= off) v += u;
    }
    int ex = __shfl_up(v, 1);
    if (lane == 0) ex = 0;
    if (lane < N_TILES) tile_sums[lane] = ex;
}

__global__ __launch_bounds__(256) void scan_pass_c(
    const int* __restrict__ cnt, const int* __restrict__ tile_offs,
    int* __restrict__ row_ptr)
{
    __shared__ int spart[256];
    int t = threadIdx.x;
    int base = blockIdx.x * SCAN_TILE + t * 8;
    int loc[8];
    int s = 0;
    #pragma unroll
    for (int q = 0; q < 8; ++q) {
        int i = base + q;
        int c = (i < N_NODES) ? cnt[i] : 0;
        loc[q] = s; s += c;
    }
    spart[t] = s;
    __syncthreads();
    for (int off = 1; off < 256; off <<= 1) {
        int v = (t >= off) ? spart[t - off] : 0;
        __syncthreads();
        spart[t] += v;
        __syncthreads();
    }
    int exoff = tile_offs[blockIdx.x] + spart[t] - s;
    #pragma unroll
    for (int q = 0; q < 8; ++q) {
        int i = base + q;
        if (i <= N_NODES) row_ptr[i] = exoff + loc[q];
    }
}

// scatter via countdown on cnt (scan passes only READ cnt) -> no second memset
__global__ __launch_bounds__(256) void scatter_kernel(
    const int* __restrict__ rows, const int* __restrict__ cols,
    const float* __restrict__ vals, const int* __restrict__ row_ptr,
    int* __restrict__ cnt, int2* __restrict__ edges)
{
    int e = blockIdx.x * 256 + threadIdx.x;
    int r = rows[e];
    int pos = row_ptr[r] + atomicSub(&cnt[r], 1) - 1;
    edges[pos] = make_int2(cols[e], __float_as_int(vals[e]));
}

// ---------------------------------------------------------------------------
// Slice SpMM: block (g, s=blockIdx%8) handles rows [g*32, g*32+32) for
// slice s (16 cols). 8-lane group per row, one unsigned (2 bf16 cols)/lane.
// x-slice (3.2 MB) is L2-resident on XCD s; edge descriptors are loaded
// nontemporal (8 per group, shfl-broadcast); side stores nontemporal.
// ---------------------------------------------------------------------------
__global__ __launch_bounds__(256) void spmm_slice(
    const int* __restrict__ row_ptr, const int2* __restrict__ edges,
    const unsigned* __restrict__ xs, unsigned* __restrict__ sides)
{
    const int s = blockIdx.x & 7;
    const int g = blockIdx.x >> 3;
    const int t = threadIdx.x;
    const int l = t & 7;                        // lane in 8-lane group
    const int row = g * 32 + (t >> 3);
    unsigned* sp = sides + ((size_t)s * NPAD + row) * 8 + l;
    if (row >= N_NODES) { *sp = 0u; return; }   // pad rows: zero

    const unsigned* xsl = xs + (size_t)s * NPAD * 8 + l;
    const long long* ed = (const long long*)edges;
    const int beg = row_ptr[row], end = row_ptr[row + 1];
    float a0 = 0.f, a1 = 0.f;
    int i = beg;
    const int nfull = (end - beg) & ~7;

    #define CHUNK8(E) { \
        int clo = (int)(E); \
        int chi = (int)((unsigned long long)(E) >> 32); \
        int cols[8]; float vs[8]; unsigned gv[8]; \
        _Pragma("unroll") \
        for (int u = 0; u < 8; ++u) { \
            cols[u] = __shfl(clo, u, 8); \
            vs[u]   = __int_as_float(__shfl(chi, u, 8)); \
        } \
        _Pragma("unroll") \
        for (int u = 0; u < 8; ++u) gv[u] = xsl[(size_t)cols[u] * 8]; \
        _Pragma("unroll") \
        for (int u = 0; u < 8; ++u) { \
            float lo, hi; UNPK(gv[u], lo, hi); \
            a0 += vs[u] * lo; a1 += vs[u] * hi; \
        } }

    if (nfull) {
        long long e = __builtin_nontemporal_load(ed + i + l);
        for (int c = 8; c < nfull; c += 8) {
            long long f = __builtin_nontemporal_load(ed + i + 8 + l);
            CHUNK8(e)
            e = f; i += 8;
        }
        CHUNK8(e)
        i += 8;
    }
    #undef CHUNK8
    for (; i < end; ++i) {                      // short tail, uniform desc
        int2 d = edges[i];
        unsigned xv = xsl[(size_t)d.x * 8];
        float v = __int_as_float(d.y), lo, hi;
        UNPK(xv, lo, hi); a0 += v * lo; a1 += v * hi;
    }
    __builtin_nontemporal_store(cvtpk(a0, a1), sp);
}

// ---------------------------------------------------------------------------
// MFMA dense: Y = leaky_relu((side+x)@W1^T + (side*x)@W2^T + b1 + b2), L2-norm
// rows, write fp32 to out[:, outoff:+128]; if write_x, write new x slice-major.
// side/x inputs are SLICE-MAJOR; LDS fragment layout and MFMA unchanged.
// ---------------------------------------------------------------------------
__global__ __launch_bounds__(256) void dense_mfma_kernel(
    const unsigned* __restrict__ sideb, const unsigned* __restrict__ xbuf,
    unsigned* __restrict__ xout,
    const unsigned* __restrict__ w1b, const unsigned* __restrict__ w2b,
    const float* __restrict__ b1, const float* __restrict__ b2,
    float* __restrict__ out, int outoff, int write_x)
{
    __shared__ __align__(16) unsigned sA1[64 * 64];   // 16 KB
    __shared__ __align__(16) unsigned sA2[64 * 64];   // 16 KB
    __shared__ float sPart[256];

    const int t = threadIdx.x;
    const int wave = t >> 6, lane = t & 63;
    const int q = lane >> 4, r = lane & 15;
    const int colbase = wave * 32;
    const int base = blockIdx.x * 64;

    // ---- B-operand fragments: lane holds W[j = colbase+nt*16+r][kk*32+q*8 ..+8)
    bf16x8 Wf[2][2][4];                   // [mat][nt][kk]
    {
        const uint4* w1p = (const uint4*)w1b;
        const uint4* w2p = (const uint4*)w2b;
        #pragma unroll
        for (int nt = 0; nt < 2; ++nt) {
            int j = colbase + nt * 16 + r;
            #pragma unroll
            for (int kk = 0; kk < 4; ++kk) {
                B8 a, b;
                a.q = w1p[j * 16 + kk * 4 + q];
                b.q = w2p[j * 16 + kk * 4 + q];
                Wf[0][nt][kk] = a.v;
                Wf[1][nt][kk] = b.v;
            }
        }
    }
    const float bias0 = b1[colbase + r]      + b2[colbase + r];
    const float bias1 = b1[colbase + 16 + r] + b2[colbase + 16 + r];

    // ---- Phase 1: build A-frags into LDS from slice-major side/x.
    // thread: node n = t&63, seg = t>>6 (cols seg*32..+32 = slices 2seg,2seg+1)
    {
        const int n = t & 63, seg = t >> 6;
        const size_t node = (size_t)(base + n);
        const uint4* sq = (const uint4*)sideb;
        const uint4* xq = (const uint4*)xbuf;
        unsigned* d1 = sA1 + n * 64;
        unsigned* d2 = sA2 + n * 64;
        const int sw = n & 7;
        #pragma unroll
        for (int j = 0; j < 4; ++j) {       // cols 32*seg + 8*j .. +8
            const int sl = 2 * seg + (j >> 1), h = j & 1;
            const size_t idx = ((size_t)sl * NPAD + node) * 2 + h;
            uint4 sv = sq[idx];
            uint4 xv = xq[idx];
            float s0,s1,s2,s3,s4,s5,s6,s7;
            float x0,x1,x2,x3,x4,x5,x6,x7;
            UNPK(sv.x, s0, s1); UNPK(sv.y, s2, s3);
            UNPK(sv.z, s4, s5); UNPK(sv.w, s6, s7);
            UNPK(xv.x, x0, x1); UNPK(xv.y, x2, x3);
            UNPK(xv.z, x4, x5); UNPK(xv.w, x6, x7);
            uint4 a1q, a2q;
            a1q.x = cvtpk(s0 + x0, s1 + x1);
            a1q.y = cvtpk(s2 + x2, s3 + x3);
            a1q.z = cvtpk(s4 + x4, s5 + x5);
            a1q.w = cvtpk(s6 + x6, s7 + x7);
            a2q.x = cvtpk(s0 * x0, s1 * x1);
            a2q.y = cvtpk(s2 * x2, s3 * x3);
            a2q.z = cvtpk(s4 * x4, s5 * x5);
            a2q.w = cvtpk(s6 * x6, s7 * x7);
            int slot = (seg * 4 + j) ^ sw;
            *(uint4*)(d1 + slot * 4) = a1q;
            *(uint4*)(d2 + slot * 4) = a2q;
        }
    }
    __syncthreads();

    // ---- Phase 2: MFMA off LDS fragments
    f32x4 acc[4][2];
    #pragma unroll
    for (int mt = 0; mt < 4; ++mt) {
        acc[mt][0] = (f32x4){0.f, 0.f, 0.f, 0.f};
        acc[mt][1] = (f32x4){0.f, 0.f, 0.f, 0.f};
    }
    int slotk[4];
    {
        const int sw = r & 7;
        #pragma unroll
        for (int kk = 0; kk < 4; ++kk) slotk[kk] = ((kk * 4 + q) ^ sw) * 4;
    }
    #pragma unroll
    for (int mt = 0; mt < 4; ++mt) {
        const unsigned* p1 = sA1 + (mt * 16 + r) * 64;
        const unsigned* p2 = sA2 + (mt * 16 + r) * 64;
        #pragma unroll
        for (int kk = 0; kk < 4; ++kk) {
            B8 a1, a2;
            a1.q = *(const uint4*)(p1 + slotk[kk]);
            a2.q = *(const uint4*)(p2 + slotk[kk]);
            acc[mt][0] = __builtin_amdgcn_mfma_f32_16x16x32_bf16(a1.v, Wf[0][0][kk], acc[mt][0], 0, 0, 0);
            acc[mt][0] = __builtin_amdgcn_mfma_f32_16x16x32_bf16(a2.v, Wf[1][0][kk], acc[mt][0], 0, 0, 0);
            acc[mt][1] = __builtin_amdgcn_mfma_f32_16x16x32_bf16(a1.v, Wf[0][1][kk], acc[mt][1], 0, 0, 0);
            acc[mt][1] = __builtin_amdgcn_mfma_f32_16x16x32_bf16(a2.v, Wf[1][1][kk], acc[mt][1], 0, 0, 0);
        }
    }

    // ---- bias + leaky_relu; per-node partial square-sums (this wave's 32 cols)
    // C/D layout: col = lane&15, row = q*4 + reg  -> node = base+mt*16+q*4+i
    #pragma unroll
    for (int mt = 0; mt < 4; ++mt) {
        #pragma unroll
        for (int i = 0; i < 4; ++i) {
            float y0 = acc[mt][0][i] + bias0; y0 = (y0 >= 0.f) ? y0 : 0.01f * y0;
            float y1 = acc[mt][1][i] + bias1; y1 = (y1 >= 0.f) ? y1 : 0.01f * y1;
            acc[mt][0][i] = y0; acc[mt][1][i] = y1;
            float s = y0 * y0 + y1 * y1;
            s += __shfl_xor(s, 1); s += __shfl_xor(s, 2);
            s += __shfl_xor(s, 4); s += __shfl_xor(s, 8);   // reduce 16 lanes (same q)
            if (r == 0) sPart[wave * 64 + mt * 16 + q * 4 + i] = s;
        }
    }
    __syncthreads();

    // ---- total norm, scale, store (out row-major; new x slice-major)
    #pragma unroll
    for (int mt = 0; mt < 4; ++mt) {
        #pragma unroll
        for (int i = 0; i < 4; ++i) {
            int nl = mt * 16 + q * 4 + i;
            float tot = sPart[nl] + sPart[64 + nl] + sPart[128 + nl] + sPart[192 + nl];
            float inv = 1.0f / fmaxf(sqrtf(tot), 1e-12f);
            int node = base + nl;
            if (node < N_NODES) {
                float y0 = acc[mt][0][i] * inv;
                float y1 = acc[mt][1][i] * inv;
                out[(size_t)node * 384 + outoff + colbase + r]      = y0;
                out[(size_t)node * 384 + outoff + colbase + 16 + r] = y1;
                if (write_x) {
                    // col colbase+r -> slice wave*2, off r; colbase+16+r -> wave*2+1
                    ((unsigned short*)xout)[((size_t)(wave * 2)     * NPAD + node) * 16 + r] = f2bs(y0);
                    ((unsigned short*)xout)[((size_t)(wave * 2 + 1) * NPAD + node) * 16 + r] = f2bs(y1);
                }
            }
        }
    }
}

// ---------------------------------------------------------------------------
extern "C" void kernel_launch(void* const* d_in, const int* in_sizes, int n_in,
                              void* d_out, int out_size, void* d_ws, size_t ws_size,
                              hipStream_t stream)
{
    const int*   adj_row  = (const int*)d_in[0];
    const int*   adj_col  = (const int*)d_in[1];
    const float* adj_vals = (const float*)d_in[2];
    const float* emb      = (const float*)d_in[3];
    const float* W1_w     = (const float*)d_in[4];
    const float* W1_b     = (const float*)d_in[5];
    const float* W2_w     = (const float*)d_in[6];
    const float* W2_b     = (const float*)d_in[7];
    float* out = (float*)d_out;

    // ---- workspace layout (bytes; all 16B-aligned). Total ~64.95 MB.
    uint8_t* w = (uint8_t*)d_ws;
    unsigned* xA      = (unsigned*)(w);                 // NPAD*128 bf16 = 25,608,192 B (slice-major)
    unsigned* xB      = (unsigned*)(w + 25608192);      // ping-pong x / side share? no: xB
    unsigned* sideb   = xB;                             // NOTE: see below
    int2*     edges   = (int2*)    (w + 51216384);      // NNZ*8 = 12,800,000 B
    unsigned* w1b     = (unsigned*)(w + 64016384);      // 2*128*128 bf16 = 65,536 B
    unsigned* w2b     = (unsigned*)(w + 64081920);      // 65,536 B
    int*      row_ptr = (int*)     (w + 64147456);      // (N+1)*4
    int*      cnt     = (int*)     (w + 64547472);      // N*4 (hist counts, then countdown)
    int*      tsums   = (int*)     (w + 64947488);      // N_TILES*4
    (void)sideb;

    // We need 3 bf16 node-buffers: x_in, side, x_out. x_out of layer 0 can
    // safely overwrite x_in AFTER dense reads it? No -- dense blocks race.
    // Use: xA = x0 (emb). side lives in xS. Layer0: spmm(xA->xS), dense reads
    // xA+xS, writes xB. Layer1: spmm(xB->xS), dense reads xB+xS, no x write.
    // xS shares the workspace slot after edges region:
    unsigned* xS = (unsigned*)(w + 64947504 + 256);     // need NPAD*256 B more
    // ^ workspace must be >= 64947760 + 25,608,192 -- keep within ws_size by
    //   instead reusing a dedicated slot: place xS right after tsums, aligned.
    xS = (unsigned*)(w + ((64947488 + 49 * 4 + 255) & ~255ull));

    prep_kernel<<<128, 256, 0, stream>>>(W1_w, W2_w, w1b, w2b, cnt);
    copy_emb_kernel<<<NPAD * 32 / 256, 256, 0, stream>>>(emb, out, xA);

    // ---- CSR build (no memsets: prep zeroed cnt; scatter counts it back down)
    hist_kernel<<<NNZ_E / 256, 256, 0, stream>>>(adj_row, cnt);
    scan_pass_a<<<N_TILES, 256, 0, stream>>>(cnt, tsums);
    scan_pass_b<<<1, 64, 0, stream>>>(tsums);
    scan_pass_c<<<N_TILES, 256, 0, stream>>>(cnt, tsums, row_ptr);
    scatter_kernel<<<NNZ_E / 256, 256, 0, stream>>>(
        adj_row, adj_col, adj_vals, row_ptr, cnt, edges);

    // ---- layer 0: side = A@x0 (slice L2-resident), y -> out[:,128:256], xB
    spmm_slice<<<(NPAD / 32) * 8, 256, 0, stream>>>(row_ptr, edges, xA, xS);
    dense_mfma_kernel<<<NPAD / 64, 256, 0, stream>>>(
        xS, xA, xB, w1b, w2b, W1_b, W2_b, out, DIM, 1);
    // ---- layer 1
    spmm_slice<<<(NPAD / 32) * 8, 256, 0, stream>>>(row_ptr, edges, xB, xS);
    dense_mfma_kernel<<<NPAD / 64, 256, 0, stream>>>(
        xS, xB, xB, w1b + 8192, w2b + 8192,
        W1_b + DIM, W2_b + DIM, out, 2 * DIM, 0);
}

// Round 7
// 651.473 us; speedup vs baseline: 1.1252x; 1.1252x over previous
//
#include <hip/hip_runtime.h>
#include <stdint.h>

#define N_NODES 100000
#define NPAD    100032
#define DIM 128
#define NNZ_E 1600000
#define SCAN_TILE 2048
#define N_TILES ((N_NODES + SCAN_TILE - 1) / SCAN_TILE)   // 49

typedef float f32x4  __attribute__((ext_vector_type(4)));
typedef short bf16x8 __attribute__((ext_vector_type(8)));

union B8 { uint4 q; unsigned u[4]; bf16x8 v; };

__device__ __forceinline__ unsigned short f2bs(float f) {   // fp32 -> bf16 RNE
    unsigned u = __builtin_bit_cast(unsigned, f);
    u = (u + 0x7fffu + ((u >> 16) & 1u)) >> 16;
    return (unsigned short)u;
}
// HW packed fp32->bf16 RNE convert: 1 instruction replaces ~8
__device__ __forceinline__ unsigned cvtpk(float lo, float hi) {
    unsigned r;
    asm("v_cvt_pk_bf16_f32 %0, %1, %2" : "=v"(r) : "v"(lo), "v"(hi));
    return r;
}
#define UNPK(u32, flo, fhi) { flo = __builtin_bit_cast(float, (unsigned)((u32) << 16)); \
                              fhi = __builtin_bit_cast(float, (unsigned)((u32) & 0xffff0000u)); }

// ---------------------------------------------------------------------------
// emb -> out[:,0:128] fp32  AND  x row-major bf16 (pad rows zeroed here)
// ---------------------------------------------------------------------------
__global__ __launch_bounds__(256) void copy_emb_kernel(
    const float* __restrict__ emb, float* __restrict__ out,
    unsigned* __restrict__ xbuf)
{
    int tid = blockIdx.x * 256 + threadIdx.x;   // NPAD*32 threads, one float4 each
    int n = tid >> 5, c = tid & 31;
    if (n < N_NODES) {
        float4 v = ((const float4*)emb)[tid];
        *((float4*)(out + (size_t)n * 384) + c) = v;
        ((uint2*)xbuf)[(size_t)n * 32 + c] = make_uint2(cvtpk(v.x, v.y), cvtpk(v.z, v.w));
    } else {
        ((uint2*)xbuf)[(size_t)n * 32 + c] = make_uint2(0u, 0u);
    }
}

// ---------------------------------------------------------------------------
// Fused prep: W fp32 -> bf16 (both layers, both matrices) + zero cnt.
// ---------------------------------------------------------------------------
__global__ __launch_bounds__(256) void prep_kernel(
    const float* __restrict__ W1, const float* __restrict__ W2,
    unsigned* __restrict__ w1b, unsigned* __restrict__ w2b,
    int* __restrict__ cnt)
{
    int tid = blockIdx.x * 256 + threadIdx.x;
    if (tid < 8192) {
        float4 a = ((const float4*)W1)[tid];
        float4 b = ((const float4*)W2)[tid];
        ((uint2*)w1b)[tid] = make_uint2(cvtpk(a.x, a.y), cvtpk(a.z, a.w));
        ((uint2*)w2b)[tid] = make_uint2(cvtpk(b.x, b.y), cvtpk(b.z, b.w));
    }
    if (tid < 25000) ((uint4*)cnt)[tid] = make_uint4(0u, 0u, 0u, 0u);  // 100000 ints
}

// ---------------------------------------------------------------------------
// CSR build: histogram -> scan -> countdown scatter
// ---------------------------------------------------------------------------
__global__ __launch_bounds__(256) void hist_kernel(
    const int* __restrict__ rows, int* __restrict__ cnt)
{
    int e = blockIdx.x * 256 + threadIdx.x;
    atomicAdd(&cnt[rows[e]], 1);
}

__global__ __launch_bounds__(256) void scan_pass_a(
    const int* __restrict__ cnt, int* __restrict__ tile_sums)
{
    __shared__ int sdata[256];
    int base = blockIdx.x * SCAN_TILE + threadIdx.x * 8;
    int s = 0;
    #pragma unroll
    for (int q = 0; q < 8; ++q) {
        int i = base + q;
        s += (i < N_NODES) ? cnt[i] : 0;
    }
    sdata[threadIdx.x] = s;
    __syncthreads();
    for (int off = 128; off >= 1; off >>= 1) {
        if (threadIdx.x < off) sdata[threadIdx.x] += sdata[threadIdx.x + off];
        __syncthreads();
    }
    if (threadIdx.x == 0) tile_sums[blockIdx.x] = sdata[0];
}

// wave-parallel exclusive scan over 49 tile sums
__global__ void scan_pass_b(int* __restrict__ tile_sums)
{
    int lane = threadIdx.x;          // 64 lanes
    int v = (lane < N_TILES) ? tile_sums[lane] : 0;
    #pragma unroll
    for (int off = 1; off < 64; off <<= 1) {
        int u = __shfl_up(v, off);
        if (lane >= off) v += u;
    }
    int ex = __shfl_up(v, 1);
    if (lane == 0) ex = 0;
    if (lane < N_TILES) tile_sums[lane] = ex;
}

__global__ __launch_bounds__(256) void scan_pass_c(
    const int* __restrict__ cnt, const int* __restrict__ tile_offs,
    int* __restrict__ row_ptr)
{
    __shared__ int spart[256];
    int t = threadIdx.x;
    int base = blockIdx.x * SCAN_TILE + t * 8;
    int loc[8];
    int s = 0;
    #pragma unroll
    for (int q = 0; q < 8; ++q) {
        int i = base + q;
        int c = (i < N_NODES) ? cnt[i] : 0;
        loc[q] = s; s += c;
    }
    spart[t] = s;
    __syncthreads();
    for (int off = 1; off < 256; off <<= 1) {
        int v = (t >= off) ? spart[t - off] : 0;
        __syncthreads();
        spart[t] += v;
        __syncthreads();
    }
    int exoff = tile_offs[blockIdx.x] + spart[t] - s;
    #pragma unroll
    for (int q = 0; q < 8; ++q) {
        int i = base + q;
        if (i <= N_NODES) row_ptr[i] = exoff + loc[q];
    }
}

// scatter via countdown on cnt (scan passes only READ cnt) -> no second memset
__global__ __launch_bounds__(256) void scatter_kernel(
    const int* __restrict__ rows, const int* __restrict__ cols,
    const float* __restrict__ vals, const int* __restrict__ row_ptr,
    int* __restrict__ cnt, int2* __restrict__ edges)
{
    int e = blockIdx.x * 256 + threadIdx.x;
    int r = rows[e];
    int pos = row_ptr[r] + atomicSub(&cnt[r], 1) - 1;
    edges[pos] = make_int2(cols[e], __float_as_int(vals[e]));
}

// ---------------------------------------------------------------------------
// FUSED layer v2: 16 nodes per block (grid NPAD/16 = 6252 -> ~8 blocks/CU,
// full wave occupancy; fixes r3's 4-node-serial latency failure).
// Phase 1: 16 groups x 16 lanes; group G owns node base+G (NO serial node
//   loop). Lane l gathers uint4 (cols l*8..l*8+7) per edge at 256B/edge
//   granularity (r6 showed smaller granules regress). Edge descs loaded
//   coalesced 16/group, shfl-16 broadcast. a1=(s+x), a2=(s*x) -> LDS with
//   XOR slot swizzle (slot = l ^ (G&7)) -- conflict-free write & read.
// Phase 2: wave w owns cols [w*32,+32); single 16-row MFMA tile, K=128 x
//   2 matrices = 16 MFMA/wave. Bias, leaky, row L2-norm, out + optional
//   ping-pong x write. MFMA phase of resident blocks overlaps gather
//   latency of others (layer ~ max(gather, dense), not sum), and the
//   side HBM round-trip (51 MB/layer) is gone.
// ---------------------------------------------------------------------------
__global__ __launch_bounds__(256) void fused_layer_kernel(
    const int* __restrict__ row_ptr, const int2* __restrict__ edges,
    const unsigned* __restrict__ xin, unsigned* __restrict__ xout,
    const unsigned* __restrict__ w1b, const unsigned* __restrict__ w2b,
    const float* __restrict__ b1, const float* __restrict__ b2,
    float* __restrict__ out, int outoff, int write_x)
{
    __shared__ __align__(16) unsigned sA1[16 * 64];   // 4 KB
    __shared__ __align__(16) unsigned sA2[16 * 64];   // 4 KB
    __shared__ float sPart[64];                       // [wave][16 nodes]

    const int t = threadIdx.x;
    const int wave = t >> 6, lane = t & 63;
    const int q = lane >> 4, r = lane & 15;
    const int G = t >> 4;          // 16-lane group 0..15 = local node
    const int l = t & 15;          // lane within group
    const int colbase = wave * 32;
    const int base = blockIdx.x * 16;
    const uint4* xin4 = (const uint4*)xin;

    // ---- Phase 1: gather this group's node, build A-frags into LDS
    {
        const int node = base + G;
        float s0=0.f,s1=0.f,s2=0.f,s3=0.f,s4=0.f,s5=0.f,s6=0.f,s7=0.f;
        float x0=0.f,x1=0.f,x2=0.f,x3=0.f,x4=0.f,x5=0.f,x6=0.f,x7=0.f;
        if (node < N_NODES) {
            const int beg = row_ptr[node], end = row_ptr[node + 1];
            const int cnt = end - beg;
            const int nb = cnt >> 4;
            #define GEDGE(u) { \
                int col = __shfl(e.x, (u), 16); \
                float v = __int_as_float(__shfl(e.y, (u), 16)); \
                uint4 xv = xin4[(size_t)col * 16 + l]; \
                float lo, hi; \
                UNPK(xv.x, lo, hi); s0 += v * lo; s1 += v * hi; \
                UNPK(xv.y, lo, hi); s2 += v * lo; s3 += v * hi; \
                UNPK(xv.z, lo, hi); s4 += v * lo; s5 += v * hi; \
                UNPK(xv.w, lo, hi); s6 += v * lo; s7 += v * hi; }
            for (int b = 0; b < nb; ++b) {
                int2 e = edges[beg + b * 16 + l];   // coalesced 128B per group
                GEDGE(0)  GEDGE(1)  GEDGE(2)  GEDGE(3)
                GEDGE(4)  GEDGE(5)  GEDGE(6)  GEDGE(7)
                GEDGE(8)  GEDGE(9)  GEDGE(10) GEDGE(11)
                GEDGE(12) GEDGE(13) GEDGE(14) GEDGE(15)
            }
            const int rem = cnt & 15;
            if (rem) {
                int idx = beg + nb * 16 + l;
                int2 e = edges[idx < end ? idx : end - 1];
                for (int u = 0; u < rem; ++u) GEDGE(u)
            }
            #undef GEDGE
            uint4 xv = xin4[(size_t)node * 16 + l];
            UNPK(xv.x, x0, x1); UNPK(xv.y, x2, x3);
            UNPK(xv.z, x4, x5); UNPK(xv.w, x6, x7);
        }
        uint4 a1q, a2q;
        a1q.x = cvtpk(s0 + x0, s1 + x1);
        a1q.y = cvtpk(s2 + x2, s3 + x3);
        a1q.z = cvtpk(s4 + x4, s5 + x5);
        a1q.w = cvtpk(s6 + x6, s7 + x7);
        a2q.x = cvtpk(s0 * x0, s1 * x1);
        a2q.y = cvtpk(s2 * x2, s3 * x3);
        a2q.z = cvtpk(s4 * x4, s5 * x5);
        a2q.w = cvtpk(s6 * x6, s7 * x7);
        const int slot = l ^ (G & 7);
        *(uint4*)(sA1 + G * 64 + slot * 4) = a1q;
        *(uint4*)(sA2 + G * 64 + slot * 4) = a2q;
    }

    // ---- B-operand fragments (issued after gather: L2-hot, cheap)
    bf16x8 Wf[2][2][4];                   // [mat][nt][kk]
    {
        const uint4* w1p = (const uint4*)w1b;
        const uint4* w2p = (const uint4*)w2b;
        #pragma unroll
        for (int nt = 0; nt < 2; ++nt) {
            int j = colbase + nt * 16 + r;
            #pragma unroll
            for (int kk = 0; kk < 4; ++kk) {
                B8 a, b;
                a.q = w1p[j * 16 + kk * 4 + q];
                b.q = w2p[j * 16 + kk * 4 + q];
                Wf[0][nt][kk] = a.v;
                Wf[1][nt][kk] = b.v;
            }
        }
    }
    const float bias0 = b1[colbase + r]      + b2[colbase + r];
    const float bias1 = b1[colbase + 16 + r] + b2[colbase + 16 + r];
    __syncthreads();

    // ---- Phase 2: one 16-row MFMA tile per wave (A-row = r, k = kk*32+q*8)
    f32x4 acc0 = (f32x4){0.f, 0.f, 0.f, 0.f};
    f32x4 acc1 = (f32x4){0.f, 0.f, 0.f, 0.f};
    {
        const int sw = r & 7;
        const unsigned* p1 = sA1 + r * 64;
        const unsigned* p2 = sA2 + r * 64;
        #pragma unroll
        for (int kk = 0; kk < 4; ++kk) {
            const int sk = ((kk * 4 + q) ^ sw) * 4;
            B8 a1, a2;
            a1.q = *(const uint4*)(p1 + sk);
            a2.q = *(const uint4*)(p2 + sk);
            acc0 = __builtin_amdgcn_mfma_f32_16x16x32_bf16(a1.v, Wf[0][0][kk], acc0, 0, 0, 0);
            acc0 = __builtin_amdgcn_mfma_f32_16x16x32_bf16(a2.v, Wf[1][0][kk], acc0, 0, 0, 0);
            acc1 = __builtin_amdgcn_mfma_f32_16x16x32_bf16(a1.v, Wf[0][1][kk], acc1, 0, 0, 0);
            acc1 = __builtin_amdgcn_mfma_f32_16x16x32_bf16(a2.v, Wf[1][1][kk], acc1, 0, 0, 0);
        }
    }

    // ---- bias + leaky_relu; per-node partial square-sums (this wave's 32 cols)
    // C/D layout: col = lane&15, row = q*4 + reg  -> local node = q*4 + i
    #pragma unroll
    for (int i = 0; i < 4; ++i) {
        float y0 = acc0[i] + bias0; y0 = (y0 >= 0.f) ? y0 : 0.01f * y0;
        float y1 = acc1[i] + bias1; y1 = (y1 >= 0.f) ? y1 : 0.01f * y1;
        acc0[i] = y0; acc1[i] = y1;
        float s = y0 * y0 + y1 * y1;
        s += __shfl_xor(s, 1); s += __shfl_xor(s, 2);
        s += __shfl_xor(s, 4); s += __shfl_xor(s, 8);   // reduce 16 lanes (same q)
        if (r == 0) sPart[wave * 16 + q * 4 + i] = s;
    }
    __syncthreads();

    // ---- total norm, scale, store (out fp32 row-major; new x bf16 row-major)
    #pragma unroll
    for (int i = 0; i < 4; ++i) {
        int nl = q * 4 + i;
        float tot = sPart[nl] + sPart[16 + nl] + sPart[32 + nl] + sPart[48 + nl];
        float inv = 1.0f / fmaxf(sqrtf(tot), 1e-12f);
        int node = base + nl;
        if (node < N_NODES) {
            float y0 = acc0[i] * inv;
            float y1 = acc1[i] * inv;
            out[(size_t)node * 384 + outoff + colbase + r]      = y0;
            out[(size_t)node * 384 + outoff + colbase + 16 + r] = y1;
            if (write_x) {
                ((unsigned short*)xout)[(size_t)node * 128 + colbase + r]      = f2bs(y0);
                ((unsigned short*)xout)[(size_t)node * 128 + colbase + 16 + r] = f2bs(y1);
            }
        }
    }
}

// ---------------------------------------------------------------------------
extern "C" void kernel_launch(void* const* d_in, const int* in_sizes, int n_in,
                              void* d_out, int out_size, void* d_ws, size_t ws_size,
                              hipStream_t stream)
{
    const int*   adj_row  = (const int*)d_in[0];
    const int*   adj_col  = (const int*)d_in[1];
    const float* adj_vals = (const float*)d_in[2];
    const float* emb      = (const float*)d_in[3];
    const float* W1_w     = (const float*)d_in[4];
    const float* W1_b     = (const float*)d_in[5];
    const float* W2_w     = (const float*)d_in[6];
    const float* W2_b     = (const float*)d_in[7];
    float* out = (float*)d_out;

    // ---- workspace layout (bytes; all 16B-aligned). Total ~64.95 MB.
    uint8_t* w = (uint8_t*)d_ws;
    unsigned* xA      = (unsigned*)(w);                 // NPAD*128 bf16 = 25,608,192 B
    unsigned* xB      = (unsigned*)(w + 25608192);      // ping-pong x
    int2*     edges   = (int2*)    (w + 51216384);      // NNZ*8 = 12,800,000 B
    unsigned* w1b     = (unsigned*)(w + 64016384);      // 2*128*128 bf16 = 65,536 B
    unsigned* w2b     = (unsigned*)(w + 64081920);      // 65,536 B
    int*      row_ptr = (int*)     (w + 64147456);      // (N+1)*4
    int*      cnt     = (int*)     (w + 64547472);      // N*4 (hist counts, then countdown)
    int*      tsums   = (int*)     (w + 64947488);      // N_TILES*4

    prep_kernel<<<128, 256, 0, stream>>>(W1_w, W2_w, w1b, w2b, cnt);
    copy_emb_kernel<<<NPAD * 32 / 256, 256, 0, stream>>>(emb, out, xA);

    // ---- CSR build (no memsets: prep zeroed cnt; scatter counts it back down)
    hist_kernel<<<NNZ_E / 256, 256, 0, stream>>>(adj_row, cnt);
    scan_pass_a<<<N_TILES, 256, 0, stream>>>(cnt, tsums);
    scan_pass_b<<<1, 64, 0, stream>>>(tsums);
    scan_pass_c<<<N_TILES, 256, 0, stream>>>(cnt, tsums, row_ptr);
    scatter_kernel<<<NNZ_E / 256, 256, 0, stream>>>(
        adj_row, adj_col, adj_vals, row_ptr, cnt, edges);

    // ---- fused layers: L0 reads xA writes xB (+out[:,128:256]);
    //                    L1 reads xB (+out[:,256:384])
    fused_layer_kernel<<<NPAD / 16, 256, 0, stream>>>(
        row_ptr, edges, xA, xB, w1b, w2b, W1_b, W2_b, out, DIM, 1);
    fused_layer_kernel<<<NPAD / 16, 256, 0, stream>>>(
        row_ptr, edges, xB, xB, w1b + 8192, w2b + 8192,
        W1_b + DIM, W2_b + DIM, out, 2 * DIM, 0);
}